// Round 4
// baseline (139.937 us; speedup 1.0000x reference)
//
#include <hip/hip_runtime.h>
#include <math.h>

// Problem constants (from reference)
#define B      512
#define DF     2048
#define DA     312
#define NTHR   320   // 5 waves; threads 0..311 each own one output column
#define RT     8     // rows per block tile in the GEMM

// ---------------------------------------------------------------------------
// Wave (64-lane) reduction helpers
// ---------------------------------------------------------------------------
__device__ __forceinline__ float wave_max_f(float v) {
  #pragma unroll
  for (int off = 32; off >= 1; off >>= 1)
    v = fmaxf(v, __shfl_down(v, off));
  return v;
}

__device__ __forceinline__ double wave_sum_d(double v) {
  #pragma unroll
  for (int off = 32; off >= 1; off >>= 1)
    v += __shfl_down(v, off);
  return v;
}

// ---------------------------------------------------------------------------
// K1: split-K GEMM partials, no LDS, compile-time k-chunk for deep unroll.
// Block (bx, by): rows bx*RT..+RT, k-chunk [by*KC, (by+1)*KC), KC = DF/KSPL.
// Thread c owns one column: W reads lane-contiguous (coalesced dwords).
// x addresses are wave-uniform -> scalar loads; FMA = v_fmac vacc, s_x, v_w.
// Outer unroll 2 x inner 16 => 32 independent W loads in flight per wave.
// KSPL=32 -> 2048 blocks -> ~6 blocks/CU resident, ~30 waves/CU.
// ---------------------------------------------------------------------------
template <int KSPL>
__global__ __launch_bounds__(NTHR) void gemm_partial_kernel(
    const float* __restrict__ x_f, const float* __restrict__ W,
    float* __restrict__ part) {
  constexpr int KC = DF / KSPL;
  const int c    = threadIdx.x;
  const int row0 = blockIdx.x * RT;
  const int k0   = blockIdx.y * KC;

  if (c >= DA) return;

  float acc[RT];
  #pragma unroll
  for (int r = 0; r < RT; ++r) acc[r] = 0.f;

  const float* Wp = W + (size_t)k0 * DA + c;
  const float* xp = x_f + (size_t)row0 * DF + k0;

  #pragma unroll 2
  for (int k = 0; k < KC; k += 16) {
    float w[16];
    #pragma unroll
    for (int j = 0; j < 16; ++j) w[j] = Wp[(size_t)(k + j) * DA];
    #pragma unroll
    for (int r = 0; r < RT; ++r) {
      const float* xr = xp + (size_t)r * DF + k;  // wave-uniform -> s_load
      #pragma unroll
      for (int j = 0; j < 16; ++j) acc[r] = fmaf(xr[j], w[j], acc[r]);
    }
  }

  #pragma unroll
  for (int r = 0; r < RT; ++r)
    part[((size_t)blockIdx.y * B + row0 + r) * DA + c] = acc[r];
}

// ---------------------------------------------------------------------------
// K2 (fused with pair reduce): per-row reduce partials + bias,
//   S_row = sum_d pre - DA*(max + log(sum exp(pre-max)))   (double accum)
// then arrival counter; the LAST block computes
//   loss = sum_{i<j, lbl_i==lbl_j} (S_j - S_i) / count
//        = sum_i (2*rank_i - m_i + 1) * S_i / (0.5 * sum_i (m_i - 1))
// where rank_i = #{j<i: lbl_j==lbl_i}, m_i = class size of row i.
// Cross-XCD visibility: agent-scope release stores of S + acq_rel counter +
// agent-scope acquire loads in the last block.
// ---------------------------------------------------------------------------
template <int KSPL>
__global__ __launch_bounds__(NTHR) void row_stats_fused_kernel(
    const float* __restrict__ part, const float* __restrict__ b,
    const int* __restrict__ labels, double* __restrict__ S,
    unsigned int* __restrict__ counter, float* __restrict__ out) {
  __shared__ float  red_f[8];
  __shared__ double red_d[16];
  __shared__ long long red_i[8];
  __shared__ float  bcast_max;
  __shared__ int    is_last;
  __shared__ double Ss[B];
  __shared__ int    Ls[B];

  const int tid  = threadIdx.x;
  const int wid  = tid >> 6;
  const int lane = tid & 63;
  const int row  = blockIdx.x;

  // ---- per-row pre-activation from partials ----
  float v = -INFINITY;
  if (tid < DA) {
    float s = b[tid];
    #pragma unroll
    for (int p = 0; p < KSPL; ++p)
      s += part[((size_t)p * B + row) * DA + tid];
    v = s;
  }

  // block max
  float m = wave_max_f(v);
  if (lane == 0) red_f[wid] = m;
  __syncthreads();
  if (tid == 0) {
    float mm = red_f[0];
    #pragma unroll
    for (int w = 1; w < NTHR / 64; ++w) mm = fmaxf(mm, red_f[w]);
    bcast_max = mm;
  }
  __syncthreads();
  const float rowmax = bcast_max;

  // double-precision sums: exp(v - max) and raw v
  double e  = (tid < DA) ? exp((double)v - (double)rowmax) : 0.0;
  double sp = (tid < DA) ? (double)v : 0.0;
  double es = wave_sum_d(e);
  double ss = wave_sum_d(sp);
  if (lane == 0) { red_d[wid] = es; red_d[8 + wid] = ss; }
  __syncthreads();
  if (tid == 0) {
    double esum = 0.0, ssum = 0.0;
    #pragma unroll
    for (int w = 0; w < NTHR / 64; ++w) { esum += red_d[w]; ssum += red_d[8 + w]; }
    double Sv = ssum - (double)DA * ((double)rowmax + log(esum));
    __hip_atomic_store(&S[row], Sv, __ATOMIC_RELEASE, __HIP_MEMORY_SCOPE_AGENT);
    unsigned int old = __hip_atomic_fetch_add(counter, 1u, __ATOMIC_ACQ_REL,
                                              __HIP_MEMORY_SCOPE_AGENT);
    is_last = (old == B - 1) ? 1 : 0;
  }
  __syncthreads();
  if (!is_last) return;

  // ---- last block: pair reduction ----
  for (int i = tid; i < B; i += NTHR) {
    Ss[i] = __hip_atomic_load(&S[i], __ATOMIC_ACQUIRE, __HIP_MEMORY_SCOPE_AGENT);
    Ls[i] = labels[i];
  }
  __syncthreads();

  // rows tid and tid+NTHR; broadcast scan over labels (same LDS addr all lanes)
  const int i0 = tid, i1 = tid + NTHR;
  const int l0 = Ls[i0];
  const int l1 = (i1 < B) ? Ls[i1] : -1;   // -1 never matches (labels >= 0)
  int r0 = 0, m0 = 0, r1 = 0, m1 = 0;
  for (int j = 0; j < B; ++j) {
    int lj = Ls[j];
    m0 += (lj == l0);
    r0 += (lj == l0 && j < i0);
    m1 += (lj == l1);
    r1 += (lj == l1 && j < i1);
  }

  double lsum = (double)(2 * r0 - m0 + 1) * Ss[i0];
  long long pcnt = m0 - 1;                 // sum of (m_i - 1) = 2 * #pairs
  if (i1 < B) {
    lsum += (double)(2 * r1 - m1 + 1) * Ss[i1];
    pcnt += m1 - 1;
  }

  #pragma unroll
  for (int off = 32; off >= 1; off >>= 1) {
    lsum += __shfl_down(lsum, off);
    pcnt += __shfl_down(pcnt, off);
  }
  if (lane == 0) { red_d[wid] = lsum; red_i[wid] = pcnt; }
  __syncthreads();
  if (tid == 0) {
    double s = 0.0; long long c2 = 0;
    #pragma unroll
    for (int w = 0; w < NTHR / 64; ++w) { s += red_d[w]; c2 += red_i[w]; }
    double cnt = (double)(c2 / 2);
    out[0] = (float)((c2 > 0) ? s / cnt : s);
  }
}

// ---------------------------------------------------------------------------
extern "C" void kernel_launch(void* const* d_in, const int* in_sizes, int n_in,
                              void* d_out, int out_size, void* d_ws, size_t ws_size,
                              hipStream_t stream) {
  const float* x_f    = (const float*)d_in[0];   // [B, DF]
  const float* W      = (const float*)d_in[1];   // [DF, DA]
  const float* b      = (const float*)d_in[2];   // [DA]
  // d_in[3] = seen_att: cancels exactly for same-label pairs (unused)
  const int*   labels = (const int*)d_in[4];     // [B]

  // ws layout: [ part: ksplit*B*DA floats ][ S: B doubles ][ counter ]
  auto launch = [&](auto ksplit_tag) {
    constexpr int KSPL = decltype(ksplit_tag)::value;
    float*  part = (float*)d_ws;
    size_t  part_bytes = ((size_t)KSPL * B * DA * 4 + 255) & ~(size_t)255;
    double* S    = (double*)((char*)d_ws + part_bytes);
    unsigned int* counter = (unsigned int*)((char*)S + (size_t)B * 8);

    hipMemsetAsync(counter, 0, sizeof(unsigned int), stream);
    dim3 g1(B / RT, KSPL);
    gemm_partial_kernel<KSPL><<<g1, NTHR, 0, stream>>>(x_f, W, part);
    row_stats_fused_kernel<KSPL><<<B, NTHR, 0, stream>>>(part, b, labels, S,
                                                         counter, (float*)d_out);
  };

  const size_t need32 = ((size_t)32 * B * DA * 4 + 255 + 255) + (size_t)B * 8 + 64;
  if (ws_size >= need32) launch(std::integral_constant<int, 32>{});
  else                   launch(std::integral_constant<int, 4>{});
}

// Round 5
// 118.019 us; speedup vs baseline: 1.1857x; 1.1857x over previous
//
#include <hip/hip_runtime.h>
#include <math.h>

// Problem constants (from reference)
#define B      512
#define DF     2048
#define DA     312
#define NTHR   320   // 5 waves
#define RT     16    // rows per block tile in the GEMM
#define KSPL   16    // k-split factor (grid.y)
#define KC     (DF / KSPL)   // 128

// ---------------------------------------------------------------------------
// Wave (64-lane) reduction helpers
// ---------------------------------------------------------------------------
__device__ __forceinline__ float wave_max_f(float v) {
  #pragma unroll
  for (int off = 32; off >= 1; off >>= 1)
    v = fmaxf(v, __shfl_down(v, off));
  return v;
}

__device__ __forceinline__ double wave_sum_d(double v) {
  #pragma unroll
  for (int off = 32; off >= 1; off >>= 1)
    v += __shfl_down(v, off);
  return v;
}

// ---------------------------------------------------------------------------
// K1: split-K GEMM partials, all-VGPR pipeline (no LDS, no scalar x loads).
// Wave layout: lane = (rg<<4) | cg ; cg in [0,16) owns 4 consecutive columns
// (float4 W loads: 16 lanes x 16B = one coalesced 256B transaction; the 4 rg
// groups read duplicate addresses -> merged by the coalescer). rg in [0,4)
// owns rows row0+rg+4*rr, rr in [0,4) (float4 x loads along k, per-lane).
// Inner 4-k chunk: 4 W float4 + 4 x float4 loads -> 64 FMAs, operands all
// VGPR-resident. unroll 2 => 16 x 16B loads in flight per lane.
// Wave w covers columns 64w..64w+63; wave 4 tail-masked (cols 312..319).
// ---------------------------------------------------------------------------
__global__ __launch_bounds__(NTHR) void gemm_partial_kernel(
    const float* __restrict__ x_f, const float* __restrict__ W,
    float* __restrict__ part) {
  const int tid  = threadIdx.x;
  const int wave = tid >> 6;
  const int lane = tid & 63;
  const int cg   = lane & 15;
  const int rg   = lane >> 4;
  const int row0 = blockIdx.x * RT;
  const int k0   = blockIdx.y * KC;

  const int  cbase  = wave * 64 + cg * 4;
  const bool cvalid = (cbase < DA);
  const int  cw     = cvalid ? cbase : (DA - 4);  // clamp: safe loads, masked store

  float4 acc[4];
  #pragma unroll
  for (int rr = 0; rr < 4; ++rr) acc[rr] = make_float4(0.f, 0.f, 0.f, 0.f);

  const float* Wp = W + (size_t)k0 * DA + cw;
  const float* xp = x_f + (size_t)(row0 + rg) * DF + k0;

  #pragma unroll 2
  for (int k = 0; k < KC; k += 4) {
    float4 wv0 = *(const float4*)(Wp + (size_t)(k + 0) * DA);
    float4 wv1 = *(const float4*)(Wp + (size_t)(k + 1) * DA);
    float4 wv2 = *(const float4*)(Wp + (size_t)(k + 2) * DA);
    float4 wv3 = *(const float4*)(Wp + (size_t)(k + 3) * DA);
    float4 xv[4];
    #pragma unroll
    for (int rr = 0; rr < 4; ++rr)
      xv[rr] = *(const float4*)(xp + (size_t)(4 * rr) * DF + k);

    #pragma unroll
    for (int rr = 0; rr < 4; ++rr) {
      acc[rr].x = fmaf(xv[rr].x, wv0.x, acc[rr].x);
      acc[rr].y = fmaf(xv[rr].x, wv0.y, acc[rr].y);
      acc[rr].z = fmaf(xv[rr].x, wv0.z, acc[rr].z);
      acc[rr].w = fmaf(xv[rr].x, wv0.w, acc[rr].w);
      acc[rr].x = fmaf(xv[rr].y, wv1.x, acc[rr].x);
      acc[rr].y = fmaf(xv[rr].y, wv1.y, acc[rr].y);
      acc[rr].z = fmaf(xv[rr].y, wv1.z, acc[rr].z);
      acc[rr].w = fmaf(xv[rr].y, wv1.w, acc[rr].w);
      acc[rr].x = fmaf(xv[rr].z, wv2.x, acc[rr].x);
      acc[rr].y = fmaf(xv[rr].z, wv2.y, acc[rr].y);
      acc[rr].z = fmaf(xv[rr].z, wv2.z, acc[rr].z);
      acc[rr].w = fmaf(xv[rr].z, wv2.w, acc[rr].w);
      acc[rr].x = fmaf(xv[rr].w, wv3.x, acc[rr].x);
      acc[rr].y = fmaf(xv[rr].w, wv3.y, acc[rr].y);
      acc[rr].z = fmaf(xv[rr].w, wv3.z, acc[rr].z);
      acc[rr].w = fmaf(xv[rr].w, wv3.w, acc[rr].w);
    }
  }

  if (cvalid) {
    #pragma unroll
    for (int rr = 0; rr < 4; ++rr) {
      const int row = row0 + rg + 4 * rr;
      *(float4*)(part + ((size_t)blockIdx.y * B + row) * DA + cbase) = acc[rr];
    }
  }
}

// ---------------------------------------------------------------------------
// K2: per-row reduce partials + bias, then
//     S_i = sum_d pre - DA*(max + log(sum exp(pre-max)))   (double accum)
// One block per row, 320 threads, thread c owns column c. KSPL unrolled ->
// 16 independent strided (coalesced) loads in flight.
// ---------------------------------------------------------------------------
__global__ __launch_bounds__(NTHR) void row_stats_kernel(
    const float* __restrict__ part, const float* __restrict__ b,
    double* __restrict__ S) {
  __shared__ float  red_f[8];
  __shared__ double red_d[16];
  __shared__ float  bcast_max;

  const int tid  = threadIdx.x;
  const int wid  = tid >> 6;
  const int lane = tid & 63;
  const int row  = blockIdx.x;

  float v = -INFINITY;
  if (tid < DA) {
    float s = b[tid];
    #pragma unroll
    for (int p = 0; p < KSPL; ++p)
      s += part[((size_t)p * B + row) * DA + tid];
    v = s;
  }

  // block max
  float m = wave_max_f(v);
  if (lane == 0) red_f[wid] = m;
  __syncthreads();
  if (tid == 0) {
    float mm = red_f[0];
    #pragma unroll
    for (int w = 1; w < NTHR / 64; ++w) mm = fmaxf(mm, red_f[w]);
    bcast_max = mm;
  }
  __syncthreads();
  const float rowmax = bcast_max;

  // double-precision sums: exp(v - max) and raw v
  double e  = (tid < DA) ? exp((double)v - (double)rowmax) : 0.0;
  double sp = (tid < DA) ? (double)v : 0.0;
  double es = wave_sum_d(e);
  double ss = wave_sum_d(sp);
  if (lane == 0) { red_d[wid] = es; red_d[8 + wid] = ss; }
  __syncthreads();
  if (tid == 0) {
    double esum = 0.0, ssum = 0.0;
    #pragma unroll
    for (int w = 0; w < NTHR / 64; ++w) { esum += red_d[w]; ssum += red_d[8 + w]; }
    S[row] = ssum - (double)DA * ((double)rowmax + log(esum));
  }
}

// ---------------------------------------------------------------------------
// K3: loss = sum_{i<j, lbl_i==lbl_j} (S_j - S_i) / count
// One block, 1024 threads; S and labels cached in LDS. Exact (double).
// ---------------------------------------------------------------------------
__global__ __launch_bounds__(1024) void pair_reduce_kernel(
    const double* __restrict__ S, const int* __restrict__ labels,
    float* __restrict__ out) {
  __shared__ double    Ss[B];
  __shared__ int       Ls[B];
  __shared__ double    red_d[16];
  __shared__ long long red_i[16];

  const int tid = threadIdx.x;
  if (tid < B) { Ss[tid] = S[tid]; Ls[tid] = labels[tid]; }
  __syncthreads();

  double lsum = 0.0;
  long long lcnt = 0;
  for (int p = tid; p < B * B; p += 1024) {
    int i = p >> 9;          // p / 512
    int j = p & (B - 1);     // p % 512
    if (j > i && Ls[i] == Ls[j]) { lsum += Ss[j] - Ss[i]; lcnt++; }
  }

  #pragma unroll
  for (int off = 32; off >= 1; off >>= 1) {
    lsum += __shfl_down(lsum, off);
    lcnt += __shfl_down(lcnt, off);
  }
  const int wid = tid >> 6, lane = tid & 63;
  if (lane == 0) { red_d[wid] = lsum; red_i[wid] = lcnt; }
  __syncthreads();
  if (tid == 0) {
    double s = 0.0; long long c = 0;
    #pragma unroll
    for (int w = 0; w < 16; ++w) { s += red_d[w]; c += red_i[w]; }
    out[0] = (float)((c > 0) ? s / (double)c : s);
  }
}

// ---------------------------------------------------------------------------
extern "C" void kernel_launch(void* const* d_in, const int* in_sizes, int n_in,
                              void* d_out, int out_size, void* d_ws, size_t ws_size,
                              hipStream_t stream) {
  const float* x_f    = (const float*)d_in[0];   // [B, DF]
  const float* W      = (const float*)d_in[1];   // [DF, DA]
  const float* b      = (const float*)d_in[2];   // [DA]
  // d_in[3] = seen_att: cancels exactly for same-label pairs (unused)
  const int*   labels = (const int*)d_in[4];     // [B]

  // ws layout: [ part: KSPL*B*DA floats ][ S: B doubles ]
  float*  part = (float*)d_ws;
  size_t  part_bytes = ((size_t)KSPL * B * DA * 4 + 255) & ~(size_t)255;
  double* S    = (double*)((char*)d_ws + part_bytes);

  dim3 g1(B / RT, KSPL);
  gemm_partial_kernel<<<g1, NTHR, 0, stream>>>(x_f, W, part);
  row_stats_kernel<<<B, NTHR, 0, stream>>>(part, b, S);
  pair_reduce_kernel<<<1, 1024, 0, stream>>>(S, labels, (float*)d_out);
}

// Round 6
// 115.104 us; speedup vs baseline: 1.2157x; 1.0253x over previous
//
#include <hip/hip_runtime.h>
#include <math.h>

// Problem constants (from reference)
#define B      512
#define DF     2048
#define DA     312
#define NTHR   320   // 5 waves
#define RT     16    // rows per block tile in the GEMM
#define KSPL   32    // k-split factor (grid.y)
#define KC     (DF / KSPL)   // 64

// ---------------------------------------------------------------------------
// Wave (64-lane) reduction helpers
// ---------------------------------------------------------------------------
__device__ __forceinline__ float wave_max_f(float v) {
  #pragma unroll
  for (int off = 32; off >= 1; off >>= 1)
    v = fmaxf(v, __shfl_down(v, off));
  return v;
}

__device__ __forceinline__ double wave_sum_d(double v) {
  #pragma unroll
  for (int off = 32; off >= 1; off >>= 1)
    v += __shfl_down(v, off);
  return v;
}

// ---------------------------------------------------------------------------
// K1: split-K GEMM partials, all-VGPR pipeline (same structure as round 5,
// which removed K1 from the >40us top-5). KSPL=32 -> 1024 blocks -> 4
// blocks/CU, 20 waves/CU for latency hiding (was 2 blocks/CU).
// Wave layout: lane = (rg<<4)|cg; cg owns 4 consecutive columns (float4 W
// loads, 16 lanes x 16B = one coalesced 256B transaction; rg groups read
// duplicate addresses -> merged). rg+4*rr indexes 16 rows (float4 x loads
// along k, per-lane VGPRs; no LDS, no scalar-file pressure).
// Block (0,0) also zero-inits the fused-reduction accumulators; the
// end-of-kernel release fence makes them visible to K2.
// ---------------------------------------------------------------------------
__global__ __launch_bounds__(NTHR) void gemm_partial_kernel(
    const float* __restrict__ x_f, const float* __restrict__ W,
    float* __restrict__ part, double* __restrict__ gsum,
    int* __restrict__ gcnt2, unsigned int* __restrict__ counter) {
  const int tid  = threadIdx.x;
  const int wave = tid >> 6;
  const int lane = tid & 63;
  const int cg   = lane & 15;
  const int rg   = lane >> 4;
  const int row0 = blockIdx.x * RT;
  const int k0   = blockIdx.y * KC;

  if (blockIdx.x == 0 && blockIdx.y == 0 && tid == 0) {
    *gsum = 0.0; *gcnt2 = 0; *counter = 0u;
  }

  const int  cbase  = wave * 64 + cg * 4;
  const bool cvalid = (cbase < DA);
  const int  cw     = cvalid ? cbase : (DA - 4);  // clamp: safe loads, masked store

  float4 acc[4];
  #pragma unroll
  for (int rr = 0; rr < 4; ++rr) acc[rr] = make_float4(0.f, 0.f, 0.f, 0.f);

  const float* Wp = W + (size_t)k0 * DA + cw;
  const float* xp = x_f + (size_t)(row0 + rg) * DF + k0;

  #pragma unroll 2
  for (int k = 0; k < KC; k += 4) {
    float4 wv0 = *(const float4*)(Wp + (size_t)(k + 0) * DA);
    float4 wv1 = *(const float4*)(Wp + (size_t)(k + 1) * DA);
    float4 wv2 = *(const float4*)(Wp + (size_t)(k + 2) * DA);
    float4 wv3 = *(const float4*)(Wp + (size_t)(k + 3) * DA);
    float4 xv[4];
    #pragma unroll
    for (int rr = 0; rr < 4; ++rr)
      xv[rr] = *(const float4*)(xp + (size_t)(4 * rr) * DF + k);

    #pragma unroll
    for (int rr = 0; rr < 4; ++rr) {
      acc[rr].x = fmaf(xv[rr].x, wv0.x, acc[rr].x);
      acc[rr].y = fmaf(xv[rr].x, wv0.y, acc[rr].y);
      acc[rr].z = fmaf(xv[rr].x, wv0.z, acc[rr].z);
      acc[rr].w = fmaf(xv[rr].x, wv0.w, acc[rr].w);
      acc[rr].x = fmaf(xv[rr].y, wv1.x, acc[rr].x);
      acc[rr].y = fmaf(xv[rr].y, wv1.y, acc[rr].y);
      acc[rr].z = fmaf(xv[rr].y, wv1.z, acc[rr].z);
      acc[rr].w = fmaf(xv[rr].y, wv1.w, acc[rr].w);
      acc[rr].x = fmaf(xv[rr].z, wv2.x, acc[rr].x);
      acc[rr].y = fmaf(xv[rr].z, wv2.y, acc[rr].y);
      acc[rr].z = fmaf(xv[rr].z, wv2.z, acc[rr].z);
      acc[rr].w = fmaf(xv[rr].z, wv2.w, acc[rr].w);
      acc[rr].x = fmaf(xv[rr].w, wv3.x, acc[rr].x);
      acc[rr].y = fmaf(xv[rr].w, wv3.y, acc[rr].y);
      acc[rr].z = fmaf(xv[rr].w, wv3.z, acc[rr].z);
      acc[rr].w = fmaf(xv[rr].w, wv3.w, acc[rr].w);
    }
  }

  if (cvalid) {
    #pragma unroll
    for (int rr = 0; rr < 4; ++rr) {
      const int row = row0 + rg + 4 * rr;
      *(float4*)(part + ((size_t)blockIdx.y * B + row) * DA + cbase) = acc[rr];
    }
  }
}

// ---------------------------------------------------------------------------
// K2 (fused): per-row reduce partials + bias,
//   S = sum_d pre - DA*(max + log(sum exp(pre-max)))   (double accum)
// Pair loss collapses per row (HW-validated in round 4, absmax 0.0):
//   loss_sum = sum_i (2*rank_i - m_i + 1) * S_i,  count = (1/2) sum_i (m_i-1)
// so each block publishes ONE double via atomicAdd (+ int + arrival counter;
// 3 L2 RMWs/block — no S array, no release/acquire scans). Last arriver
// divides and writes out.
// ---------------------------------------------------------------------------
__global__ __launch_bounds__(NTHR) void row_stats_fused_kernel(
    const float* __restrict__ part, const float* __restrict__ b,
    const int* __restrict__ labels, double* __restrict__ gsum,
    int* __restrict__ gcnt2, unsigned int* __restrict__ counter,
    float* __restrict__ out) {
  __shared__ float  red_f[8];
  __shared__ double red_d[16];
  __shared__ float  bcast_max;
  __shared__ int    lm, lr;   // class size m, rank r for this row

  const int tid  = threadIdx.x;
  const int wid  = tid >> 6;
  const int lane = tid & 63;
  const int row  = blockIdx.x;

  if (tid == 0) { lm = 0; lr = 0; }

  // ---- label scan (parallel): m = #{j: lbl_j==myl}, r = #{j<row: ==} ----
  const int myl = labels[row];
  int c_m = 0, c_r = 0;
  #pragma unroll
  for (int t = 0; t < 2; ++t) {
    int j = tid + t * NTHR;
    if (j < B) {
      int lj = labels[j];
      c_m += (lj == myl);
      c_r += (lj == myl && j < row);
    }
  }

  // ---- per-row pre-activation from partials ----
  float v = -INFINITY;
  if (tid < DA) {
    float s = b[tid];
    #pragma unroll
    for (int p = 0; p < KSPL; ++p)
      s += part[((size_t)p * B + row) * DA + tid];
    v = s;
  }

  __syncthreads();              // lm/lr inited
  if (c_m) atomicAdd(&lm, c_m); // LDS atomics
  if (c_r) atomicAdd(&lr, c_r);

  // block max
  float m = wave_max_f(v);
  if (lane == 0) red_f[wid] = m;
  __syncthreads();
  if (tid == 0) {
    float mm = red_f[0];
    #pragma unroll
    for (int w = 1; w < NTHR / 64; ++w) mm = fmaxf(mm, red_f[w]);
    bcast_max = mm;
  }
  __syncthreads();
  const float rowmax = bcast_max;

  // double-precision sums: exp(v - max) and raw v
  double e  = (tid < DA) ? exp((double)v - (double)rowmax) : 0.0;
  double sp = (tid < DA) ? (double)v : 0.0;
  double es = wave_sum_d(e);
  double ss = wave_sum_d(sp);
  if (lane == 0) { red_d[wid] = es; red_d[8 + wid] = ss; }
  __syncthreads();

  if (tid == 0) {
    double esum = 0.0, ssum = 0.0;
    #pragma unroll
    for (int w = 0; w < NTHR / 64; ++w) { esum += red_d[w]; ssum += red_d[8 + w]; }
    const double S = ssum - (double)DA * ((double)rowmax + log(esum));
    const double contrib = (double)(2 * lr - lm + 1) * S;

    __hip_atomic_fetch_add(gsum, contrib, __ATOMIC_RELAXED, __HIP_MEMORY_SCOPE_AGENT);
    __hip_atomic_fetch_add(gcnt2, lm - 1, __ATOMIC_RELAXED, __HIP_MEMORY_SCOPE_AGENT);
    unsigned int old = __hip_atomic_fetch_add(counter, 1u, __ATOMIC_ACQ_REL,
                                              __HIP_MEMORY_SCOPE_AGENT);
    if (old == B - 1) {
      // all blocks' RMWs reached the coherent point before their counter add
      double s = __hip_atomic_fetch_add(gsum, 0.0, __ATOMIC_RELAXED,
                                        __HIP_MEMORY_SCOPE_AGENT);
      int c2 = __hip_atomic_fetch_add(gcnt2, 0, __ATOMIC_RELAXED,
                                      __HIP_MEMORY_SCOPE_AGENT);
      out[0] = (float)((c2 > 0) ? s / (double)(c2 / 2) : s);
    }
  }
}

// ---------------------------------------------------------------------------
extern "C" void kernel_launch(void* const* d_in, const int* in_sizes, int n_in,
                              void* d_out, int out_size, void* d_ws, size_t ws_size,
                              hipStream_t stream) {
  const float* x_f    = (const float*)d_in[0];   // [B, DF]
  const float* W      = (const float*)d_in[1];   // [DF, DA]
  const float* b      = (const float*)d_in[2];   // [DA]
  // d_in[3] = seen_att: cancels exactly for same-label pairs (unused)
  const int*   labels = (const int*)d_in[4];     // [B]

  // ws layout: [ part: KSPL*B*DA floats ][ gsum d ][ gcnt2 i ][ counter u ]
  float*  part = (float*)d_ws;
  size_t  part_bytes = ((size_t)KSPL * B * DA * 4 + 255) & ~(size_t)255;
  double* gsum = (double*)((char*)d_ws + part_bytes);
  int*    gcnt2 = (int*)(gsum + 1);
  unsigned int* counter = (unsigned int*)(gcnt2 + 1);

  dim3 g1(B / RT, KSPL);
  gemm_partial_kernel<<<g1, NTHR, 0, stream>>>(x_f, W, part, gsum, gcnt2, counter);
  row_stats_fused_kernel<<<B, NTHR, 0, stream>>>(part, b, labels, gsum, gcnt2,
                                                 counter, (float*)d_out);
}